// Round 14
// baseline (335.816 us; speedup 1.0000x reference)
//
#include <hip/hip_runtime.h>
#include <hip/hip_fp16.h>

#define N_NODES 100000
#define N_EDGES 1600000
#define IN_F 128
#define HID 64
#define NBUCK 1563          // ceil(100000 / 64), 64 nodes per bucket
#define NBP 1600            // padded bucket stride
#define GS 512              // grid-stride blocks for hist_g / bin (mappings MUST match)

typedef _Float16 half8 __attribute__((ext_vector_type(8)));
typedef float f32x4 __attribute__((ext_vector_type(4)));

// ---------------- per-block bucket histogram -> u16 gcnt[g][b] (R13-proven) ----------
__global__ __launch_bounds__(256) void k_hist_g(const int* __restrict__ dst,
                                                unsigned short* __restrict__ gcnt) {
    __shared__ int h[NBP];
    for (int t = threadIdx.x; t < NBP; t += 256) h[t] = 0;
    __syncthreads();
    const int g = blockIdx.x;
    const int NQ = N_EDGES / 4;                  // 400000, exact
    const int4* dst4 = (const int4*)dst;
    for (int q = g * 256 + threadIdx.x; q < NQ; q += GS * 256) {
        int4 d4 = dst4[q];
        atomicAdd(&h[d4.x >> 6], 1);
        atomicAdd(&h[d4.y >> 6], 1);
        atomicAdd(&h[d4.z >> 6], 1);
        atomicAdd(&h[d4.w >> 6], 1);
    }
    __syncthreads();
    unsigned int* row = (unsigned int*)(gcnt + g * NBP);
    for (int t = threadIdx.x; t < NBP / 2; t += 256)
        row[t] = (unsigned)h[2 * t] | ((unsigned)h[2 * t + 1] << 16);   // packed u16 pair
}

// ---------------- per-bucket scan over blocks; 8 buckets/block, uint4 lanes (R13-proven) --
__global__ __launch_bounds__(512) void k_gbase(const unsigned short* __restrict__ gcnt,
                                               unsigned short* __restrict__ pre,
                                               int* __restrict__ bt) {
    __shared__ uint4 s[512];                     // 8 KB
    const int t = threadIdx.x;
    const int b0 = blockIdx.x * 8;               // grid 196 -> buckets 0..1567
    const int g = ((t & 63) << 3) | (t >> 6);    // rank -> block (XCD-grouped order)
    uint4 v = *(const uint4*)(gcnt + g * NBP + b0);
    uint4 run = v;
    s[t] = run;
    __syncthreads();
    for (int o = 1; o < 512; o <<= 1) {
        uint4 tt = {0u, 0u, 0u, 0u};
        if (t >= o) tt = s[t - o];
        __syncthreads();
        run.x += tt.x; run.y += tt.y; run.z += tt.z; run.w += tt.w;
        s[t] = run;
        __syncthreads();
    }
    uint4 ex = { run.x - v.x, run.y - v.y, run.z - v.z, run.w - v.w };  // exclusive, lane-safe
    *(uint4*)(pre + g * NBP + b0) = ex;
    if (t == 511) {
        bt[b0 + 0] = run.x & 0xFFFF; bt[b0 + 1] = run.x >> 16;
        bt[b0 + 2] = run.y & 0xFFFF; bt[b0 + 3] = run.y >> 16;
        bt[b0 + 4] = run.z & 0xFFFF; bt[b0 + 5] = run.z >> 16;
        bt[b0 + 6] = run.w & 0xFFFF; bt[b0 + 7] = run.w >> 16;
    }
}

// ---------------- single-block exclusive scan over bucket totals (proven) ----------
__global__ __launch_bounds__(1024) void k_bscan(const int* __restrict__ bt,
                                                int* __restrict__ bbase,
                                                int* __restrict__ off) {
    __shared__ int s[1024];
    const int t = threadIdx.x;
    int v0 = (2 * t < 1568) ? bt[2 * t] : 0;         // only 1568 buckets written
    int v1 = (2 * t + 1 < 1568) ? bt[2 * t + 1] : 0;
    int p = v0 + v1;
    s[t] = p;
    __syncthreads();
    for (int o = 1; o < 1024; o <<= 1) {
        int tt = (t >= o) ? s[t - o] : 0;
        __syncthreads();
        s[t] += tt;
        __syncthreads();
    }
    int base = s[t] - p;
    bbase[2 * t] = base;
    bbase[2 * t + 1] = base + v0;
    if (t == 0) off[N_NODES] = N_EDGES;     // CSR sentinel
}

// ---------------- bin: deterministic slots via LDS cursors; int4 loads (R13-proven) -------
__global__ __launch_bounds__(256) void k_bin(const int* __restrict__ src,
                                             const int* __restrict__ dst,
                                             const int* __restrict__ bbase,
                                             const unsigned short* __restrict__ pre,
                                             int* __restrict__ bin) {
    __shared__ int cur[NBP];
    const int g = blockIdx.x;
    const unsigned short* prow = pre + g * NBP;
    for (int t = threadIdx.x; t < NBP; t += 256)
        cur[t] = (t < NBUCK) ? (bbase[t] + (int)prow[t]) : 0;
    __syncthreads();
    const int NQ = N_EDGES / 4;
    const int4* src4 = (const int4*)src;
    const int4* dst4 = (const int4*)dst;
    for (int q = g * 256 + threadIdx.x; q < NQ; q += GS * 256) {
        int4 s4 = src4[q];
        int4 d4 = dst4[q];
        int slot;
        slot = atomicAdd(&cur[d4.x >> 6], 1); bin[slot] = ((d4.x & 63) << 17) | s4.x;
        slot = atomicAdd(&cur[d4.y >> 6], 1); bin[slot] = ((d4.y & 63) << 17) | s4.y;
        slot = atomicAdd(&cur[d4.z >> 6], 1); bin[slot] = ((d4.z & 63) << 17) | s4.z;
        slot = atomicAdd(&cur[d4.w >> 6], 1); bin[slot] = ((d4.w & 63) << 17) | s4.w;
    }
}

// ---------------- per-bucket: histogram -> off/dinv, then reorder bin -> csr (proven) ----
__global__ __launch_bounds__(256) void k_csr(const int* __restrict__ bin,
                                             const int* __restrict__ bbase,
                                             int* __restrict__ off,
                                             float* __restrict__ dinv,
                                             int* __restrict__ csr) {
    __shared__ int cnt64[64];
    __shared__ int cur64[64];
    const int b = blockIdx.x;
    if (threadIdx.x < 64) cnt64[threadIdx.x] = 0;
    __syncthreads();
    const int beg = bbase[b], end = bbase[b + 1];
    for (int i = beg + threadIdx.x; i < end; i += 256)
        atomicAdd(&cnt64[(bin[i] >> 17) & 63], 1);
    __syncthreads();
    if (threadIdx.x == 0) {
        int run = beg;
        #pragma unroll
        for (int j = 0; j < 64; ++j) {
            cur64[j] = run;
            run += cnt64[j];
        }
    }
    __syncthreads();
    if (threadIdx.x < 64) {
        int node = b * 64 + threadIdx.x;
        if (node < N_NODES) {
            off[node] = cur64[threadIdx.x];
            dinv[node] = rsqrtf((float)(cnt64[threadIdx.x] + 1));  // +1 self-loop
        }
    }
    __syncthreads();
    for (int i = beg + threadIdx.x; i < end; i += 256) {
        int v = bin[i];
        int slot = atomicAdd(&cur64[(v >> 17) & 63], 1);
        csr[slot] = v & 0x1FFFF;
    }
}

// ---------------- layer 1 GEMM via MFMA: h' = fp16((x @ W1) * dinv) (R11-proven) ----------
__global__ __launch_bounds__(256) void k_gemm1(const float* __restrict__ x,
                                               const float* __restrict__ W1,
                                               const float* __restrict__ dinv,
                                               __half* __restrict__ hout) {
    __shared__ _Float16 Wl[8192];      // 16 KB, frag-ordered: [(nt*4+kc)*64+lane][8]
    const int tid = threadIdx.x, wave = tid >> 6, lane = tid & 63;
    const int quad = lane >> 4, m = lane & 15;
    // zero row at index N_NODES (harmless; kept from R13)
    if (blockIdx.x == 0 && tid < 32) ((int*)hout)[(size_t)N_NODES * 32 + tid] = 0;
    // repack W1 into B-fragment order (one-time)
    for (int it = 0; it < 16; ++it) {
        int p = it * 256 + tid;                 // 0..4095 half2-pairs
        int j2 = p & 3, ln = (p >> 2) & 63, kc = (p >> 8) & 3, nt = p >> 10;
        int k = kc * 32 + ((ln >> 4) << 3) + j2 * 2;
        int n = nt * 16 + (ln & 15);
        Wl[p * 2]     = (_Float16)W1[k * HID + n];
        Wl[p * 2 + 1] = (_Float16)W1[(k + 1) * HID + n];
    }
    __syncthreads();
    half8 bf[16];                               // B frags in VGPRs for whole kernel
    #pragma unroll
    for (int i = 0; i < 16; ++i) bf[i] = ((const half8*)Wl)[i * 64 + lane];

    const int ngroups = NBUCK;                  // 1563 groups of 64 nodes
    for (int g = blockIdx.x; g < ngroups; g += gridDim.x) {
        const int n0 = g * 64 + wave * 16;      // this wave's 16-node tile
        if (n0 >= N_NODES) continue;            // only last group's waves 2,3
        const float4* xrow = (const float4*)(x + (size_t)(n0 + m) * IN_F);
        f32x4 acc[4] = {{0.f,0.f,0.f,0.f},{0.f,0.f,0.f,0.f},
                        {0.f,0.f,0.f,0.f},{0.f,0.f,0.f,0.f}};
        #pragma unroll
        for (int kc = 0; kc < 4; ++kc) {
            float4 p0 = xrow[kc * 8 + quad * 2 + 0];   // A[m][kc*32+quad*8 .. +3]
            float4 p1 = xrow[kc * 8 + quad * 2 + 1];   // .. +4..+7
            half8 a;
            a[0] = (_Float16)p0.x; a[1] = (_Float16)p0.y;
            a[2] = (_Float16)p0.z; a[3] = (_Float16)p0.w;
            a[4] = (_Float16)p1.x; a[5] = (_Float16)p1.y;
            a[6] = (_Float16)p1.z; a[7] = (_Float16)p1.w;
            #pragma unroll
            for (int nt = 0; nt < 4; ++nt)
                acc[nt] = __builtin_amdgcn_mfma_f32_16x16x32_f16(a, bf[nt * 4 + kc], acc[nt], 0, 0, 0);
        }
        // epilogue: D[row=quad*4+r][col=lane&15] -> h[(n0+row)*64 + nt*16 + col]
        float di[4];
        #pragma unroll
        for (int r = 0; r < 4; ++r) di[r] = dinv[n0 + quad * 4 + r];
        _Float16* hp = (_Float16*)hout;
        #pragma unroll
        for (int nt = 0; nt < 4; ++nt)
            #pragma unroll
            for (int r = 0; r < 4; ++r)
                hp[(size_t)(n0 + quad * 4 + r) * HID + nt * 16 + m] =
                    (_Float16)(acc[nt][r] * di[r]);
    }
}

// ---------------- layer 1 aggregate, feature-sliced + XCD-affine -> y = relu(...) --------
// slice s = blockIdx&7 (16 B of features); per-XCD h1-slice = 1.6 MB -> L2-resident.
// wave = 4 nodes x 16 lanes; ONE EDGE PER LANE (own csr read, own 16B row read, no shfl).
__global__ __launch_bounds__(256) void k_aggy(const __half* __restrict__ h1,
                                              const int* __restrict__ off,
                                              const int* __restrict__ csr,
                                              const float* __restrict__ dinv,
                                              const float* __restrict__ b1,
                                              __half* __restrict__ y) {
    const int tid = threadIdx.x, wave = tid >> 6, lane = tid & 63;
    const int g = lane >> 4, l = lane & 15;
    const int s = blockIdx.x & 7;                // feature slice
    const int nb = blockIdx.x >> 3;              // node block [0,6250)
    const int d = nb * 16 + wave * 4 + g;        // this group's node (exact, no tail)
    const int beg = off[d], end = off[d + 1];
    const half8* rows = (const half8*)h1;        // row r, slice s @ rows[r*8+s]
    half8 acc;
    #pragma unroll
    for (int i = 0; i < 8; ++i) acc[i] = (_Float16)0.f;
    for (int p = beg + l; p < end; p += 16) {    // per-lane independent edges
        int sr = csr[p];
        acc += rows[(size_t)sr * 8 + s];         // v_pk_add_f16 x4
    }
    float f[8];
    #pragma unroll
    for (int i = 0; i < 8; ++i) f[i] = (float)acc[i];
    #pragma unroll
    for (int o = 8; o > 0; o >>= 1) {            // fp32 reduce within 16-lane group
        #pragma unroll
        for (int i = 0; i < 8; ++i) f[i] += __shfl_xor(f[i], o, 64);
    }
    if (l == 0) {
        half8 sv = rows[(size_t)d * 8 + s];      // self-loop term
        float di = dinv[d];
        float4 ba = ((const float4*)b1)[s * 2];
        float4 bb = ((const float4*)b1)[s * 2 + 1];
        half8 outv;
        outv[0] = (_Float16)fmaxf(di * (f[0] + (float)sv[0]) + ba.x, 0.f);
        outv[1] = (_Float16)fmaxf(di * (f[1] + (float)sv[1]) + ba.y, 0.f);
        outv[2] = (_Float16)fmaxf(di * (f[2] + (float)sv[2]) + ba.z, 0.f);
        outv[3] = (_Float16)fmaxf(di * (f[3] + (float)sv[3]) + ba.w, 0.f);
        outv[4] = (_Float16)fmaxf(di * (f[4] + (float)sv[4]) + bb.x, 0.f);
        outv[5] = (_Float16)fmaxf(di * (f[5] + (float)sv[5]) + bb.y, 0.f);
        outv[6] = (_Float16)fmaxf(di * (f[6] + (float)sv[6]) + bb.z, 0.f);
        outv[7] = (_Float16)fmaxf(di * (f[7] + (float)sv[7]) + bb.w, 0.f);
        ((half8*)y)[(size_t)d * 8 + s] = outv;
    }
}

// ---------------- h2p = dinv * (y @ W2); thread per node ----------------
__global__ __launch_bounds__(256) void k_gemm2y(const __half* __restrict__ y,
                                                const float* __restrict__ W2,
                                                const float* __restrict__ dinv,
                                                float2* __restrict__ h2p) {
    __shared__ float Ws[HID * 2];
    if (threadIdx.x < HID * 2) Ws[threadIdx.x] = W2[threadIdx.x];
    __syncthreads();
    int i = blockIdx.x * 256 + threadIdx.x;
    if (i > N_NODES) return;
    if (i == N_NODES) { h2p[i] = make_float2(0.f, 0.f); return; }   // zero row for gather2
    const half8* yr = (const half8*)y + (size_t)i * 8;
    float c0 = 0.f, c1 = 0.f;
    #pragma unroll
    for (int q = 0; q < 8; ++q) {
        half8 v = yr[q];
        #pragma unroll
        for (int j = 0; j < 8; ++j) {
            float vf = (float)v[j];
            c0 += vf * Ws[(q * 8 + j) * 2];
            c1 += vf * Ws[(q * 8 + j) * 2 + 1];
        }
    }
    float di = dinv[i];
    h2p[i] = make_float2(c0 * di, c1 * di);
}

// ---------------- layer 2 gather + finalize; 4 loads in flight (R13-proven) ----------
__global__ __launch_bounds__(256) void k_gather2(const float2* __restrict__ h2p,
                                                 const int* __restrict__ off,
                                                 const int* __restrict__ csr,
                                                 const float* __restrict__ dinv,
                                                 const float* __restrict__ b2,
                                                 float* __restrict__ out) {
    int i = blockIdx.x * 256 + threadIdx.x;
    if (i >= N_NODES) return;
    int beg = off[i], end = off[i + 1];
    float2 a = h2p[i];                                // self-loop term
    for (int s = beg; s < end; s += 4) {
        int node[4];
        #pragma unroll
        for (int u = 0; u < 4; ++u) {
            int idx = s + u;
            int n = csr[min(idx, end - 1)];           // always in-bounds load
            node[u] = (idx < end) ? n : N_NODES;      // padded -> zero row
        }
        float2 v[4];
        #pragma unroll
        for (int u = 0; u < 4; ++u) v[u] = h2p[node[u]];   // 4 loads in flight
        #pragma unroll
        for (int u = 0; u < 4; ++u) { a.x += v[u].x; a.y += v[u].y; }
    }
    float di = dinv[i];
    float2 o2 = make_float2(di * a.x + b2[0], di * a.y + b2[1]);
    ((float2*)out)[i] = o2;
}

extern "C" void kernel_launch(void* const* d_in, const int* in_sizes, int n_in,
                              void* d_out, int out_size, void* d_ws, size_t ws_size,
                              hipStream_t stream) {
    const float* x  = (const float*)d_in[0];
    const int*   ei = (const int*)d_in[1];
    const float* W1 = (const float*)d_in[2];
    const float* b1 = (const float*)d_in[3];
    const float* W2 = (const float*)d_in[4];
    const float* b2 = (const float*)d_in[5];
    float* out = (float*)d_out;

    const int* src = ei;
    const int* dst = ei + N_EDGES;

    // workspace layout (int units; no aliasing; ~43.3 MB, proven >=52 MB available)
    int*            wsi   = (int*)d_ws;
    unsigned short* gcnt  = (unsigned short*)wsi;            // 512x1600 u16
    unsigned short* pre   = (unsigned short*)(wsi + 409600);
    int*            bt    = wsi + 819200;                    // 2048
    int*            bbase = wsi + 821248;                    // 2048
    int*            off   = wsi + 823296;                    // 100352 (N+1 used)
    float*          dinv  = (float*)(wsi + 923648);          // 100352
    int*            bin   = wsi + 1024000;                   // 1600000
    int*            csr   = wsi + 2624000;                   // 1600000
    __half*         h1p   = (__half*)(wsi + 4224000);        // 100001 rows x 128 B
    float2*         h2p   = (float2*)(wsi + 7424064);        // 100001 float2
    __half*         yb    = (__half*)(wsi + 7624192);        // 100000 x 64 fp16 = 12.8 MB

    dim3 B(256);
    k_hist_g <<<GS, B, 0, stream>>>(dst, gcnt);
    k_gbase  <<<196, 512, 0, stream>>>(gcnt, pre, bt);       // 196*8 = 1568 buckets
    k_bscan  <<<1, 1024, 0, stream>>>(bt, bbase, off);
    k_bin    <<<GS, B, 0, stream>>>(src, dst, bbase, pre, bin);
    k_csr    <<<NBUCK, B, 0, stream>>>(bin, bbase, off, dinv, csr);

    k_gemm1  <<<512, B, 0, stream>>>(x, W1, dinv, h1p);
    k_aggy   <<<50000, B, 0, stream>>>(h1p, off, csr, dinv, b1, yb);   // 6250 nb x 8 slices
    k_gemm2y <<<392, B, 0, stream>>>(yb, W2, dinv, h2p);
    k_gather2<<<(N_NODES + 255) / 256, B, 0, stream>>>(h2p, off, csr, dinv, b2, out);
}

// Round 15
// 180.700 us; speedup vs baseline: 1.8584x; 1.8584x over previous
//
#include <hip/hip_runtime.h>
#include <hip/hip_fp16.h>

#define N_NODES 100000
#define N_EDGES 1600000
#define IN_F 128
#define HID 64
#define NBUCK 1563          // ceil(100000 / 64), 64 nodes per bucket
#define NBP 1600            // padded bucket stride
#define GS 512              // grid-stride blocks for hist_g / bin (mappings MUST match)

typedef _Float16 half8 __attribute__((ext_vector_type(8)));
typedef _Float16 half4v __attribute__((ext_vector_type(4)));
typedef _Float16 half2v __attribute__((ext_vector_type(2)));
typedef float f32x4 __attribute__((ext_vector_type(4)));

// ---------------- per-block bucket histogram -> u16 gcnt[g][b] (R13-proven) ----------
__global__ __launch_bounds__(256) void k_hist_g(const int* __restrict__ dst,
                                                unsigned short* __restrict__ gcnt) {
    __shared__ int h[NBP];
    for (int t = threadIdx.x; t < NBP; t += 256) h[t] = 0;
    __syncthreads();
    const int g = blockIdx.x;
    const int NQ = N_EDGES / 4;                  // 400000, exact
    const int4* dst4 = (const int4*)dst;
    for (int q = g * 256 + threadIdx.x; q < NQ; q += GS * 256) {
        int4 d4 = dst4[q];
        atomicAdd(&h[d4.x >> 6], 1);
        atomicAdd(&h[d4.y >> 6], 1);
        atomicAdd(&h[d4.z >> 6], 1);
        atomicAdd(&h[d4.w >> 6], 1);
    }
    __syncthreads();
    unsigned int* row = (unsigned int*)(gcnt + g * NBP);
    for (int t = threadIdx.x; t < NBP / 2; t += 256)
        row[t] = (unsigned)h[2 * t] | ((unsigned)h[2 * t + 1] << 16);   // packed u16 pair
}

// ---------------- per-bucket scan over blocks; 8 buckets/block, uint4 lanes (R13-proven) --
__global__ __launch_bounds__(512) void k_gbase(const unsigned short* __restrict__ gcnt,
                                               unsigned short* __restrict__ pre,
                                               int* __restrict__ bt) {
    __shared__ uint4 s[512];                     // 8 KB
    const int t = threadIdx.x;
    const int b0 = blockIdx.x * 8;               // grid 196 -> buckets 0..1567
    const int g = ((t & 63) << 3) | (t >> 6);    // rank -> block (XCD-grouped order)
    uint4 v = *(const uint4*)(gcnt + g * NBP + b0);
    uint4 run = v;
    s[t] = run;
    __syncthreads();
    for (int o = 1; o < 512; o <<= 1) {
        uint4 tt = {0u, 0u, 0u, 0u};
        if (t >= o) tt = s[t - o];
        __syncthreads();
        run.x += tt.x; run.y += tt.y; run.z += tt.z; run.w += tt.w;
        s[t] = run;
        __syncthreads();
    }
    uint4 ex = { run.x - v.x, run.y - v.y, run.z - v.z, run.w - v.w };  // exclusive, lane-safe
    *(uint4*)(pre + g * NBP + b0) = ex;
    if (t == 511) {
        bt[b0 + 0] = run.x & 0xFFFF; bt[b0 + 1] = run.x >> 16;
        bt[b0 + 2] = run.y & 0xFFFF; bt[b0 + 3] = run.y >> 16;
        bt[b0 + 4] = run.z & 0xFFFF; bt[b0 + 5] = run.z >> 16;
        bt[b0 + 6] = run.w & 0xFFFF; bt[b0 + 7] = run.w >> 16;
    }
}

// ---------------- single-block exclusive scan over bucket totals (proven) ----------
__global__ __launch_bounds__(1024) void k_bscan(const int* __restrict__ bt,
                                                int* __restrict__ bbase,
                                                int* __restrict__ off) {
    __shared__ int s[1024];
    const int t = threadIdx.x;
    int v0 = (2 * t < 1568) ? bt[2 * t] : 0;         // only 1568 buckets written
    int v1 = (2 * t + 1 < 1568) ? bt[2 * t + 1] : 0;
    int p = v0 + v1;
    s[t] = p;
    __syncthreads();
    for (int o = 1; o < 1024; o <<= 1) {
        int tt = (t >= o) ? s[t - o] : 0;
        __syncthreads();
        s[t] += tt;
        __syncthreads();
    }
    int base = s[t] - p;
    bbase[2 * t] = base;
    bbase[2 * t + 1] = base + v0;
    if (t == 0) off[N_NODES] = N_EDGES;     // CSR sentinel
}

// ---------------- bin: deterministic slots via LDS cursors; int4 loads (R13-proven) -------
__global__ __launch_bounds__(256) void k_bin(const int* __restrict__ src,
                                             const int* __restrict__ dst,
                                             const int* __restrict__ bbase,
                                             const unsigned short* __restrict__ pre,
                                             int* __restrict__ bin) {
    __shared__ int cur[NBP];
    const int g = blockIdx.x;
    const unsigned short* prow = pre + g * NBP;
    for (int t = threadIdx.x; t < NBP; t += 256)
        cur[t] = (t < NBUCK) ? (bbase[t] + (int)prow[t]) : 0;
    __syncthreads();
    const int NQ = N_EDGES / 4;
    const int4* src4 = (const int4*)src;
    const int4* dst4 = (const int4*)dst;
    for (int q = g * 256 + threadIdx.x; q < NQ; q += GS * 256) {
        int4 s4 = src4[q];
        int4 d4 = dst4[q];
        int slot;
        slot = atomicAdd(&cur[d4.x >> 6], 1); bin[slot] = ((d4.x & 63) << 17) | s4.x;
        slot = atomicAdd(&cur[d4.y >> 6], 1); bin[slot] = ((d4.y & 63) << 17) | s4.y;
        slot = atomicAdd(&cur[d4.z >> 6], 1); bin[slot] = ((d4.z & 63) << 17) | s4.z;
        slot = atomicAdd(&cur[d4.w >> 6], 1); bin[slot] = ((d4.w & 63) << 17) | s4.w;
    }
}

// ---------------- per-bucket: histogram -> off/dinv, then reorder bin -> csr (proven) ----
__global__ __launch_bounds__(256) void k_csr(const int* __restrict__ bin,
                                             const int* __restrict__ bbase,
                                             int* __restrict__ off,
                                             float* __restrict__ dinv,
                                             int* __restrict__ csr) {
    __shared__ int cnt64[64];
    __shared__ int cur64[64];
    const int b = blockIdx.x;
    if (threadIdx.x < 64) cnt64[threadIdx.x] = 0;
    __syncthreads();
    const int beg = bbase[b], end = bbase[b + 1];
    for (int i = beg + threadIdx.x; i < end; i += 256)
        atomicAdd(&cnt64[(bin[i] >> 17) & 63], 1);
    __syncthreads();
    if (threadIdx.x == 0) {
        int run = beg;
        #pragma unroll
        for (int j = 0; j < 64; ++j) {
            cur64[j] = run;
            run += cnt64[j];
        }
    }
    __syncthreads();
    if (threadIdx.x < 64) {
        int node = b * 64 + threadIdx.x;
        if (node < N_NODES) {
            off[node] = cur64[threadIdx.x];
            dinv[node] = rsqrtf((float)(cnt64[threadIdx.x] + 1));  // +1 self-loop
        }
    }
    __syncthreads();
    for (int i = beg + threadIdx.x; i < end; i += 256) {
        int v = bin[i];
        int slot = atomicAdd(&cur64[(v >> 17) & 63], 1);
        csr[slot] = v & 0x1FFFF;
    }
}

// ---------------- layer 1 GEMM via MFMA: h' = fp16((x @ W1) * dinv) (R11-proven) ----------
__global__ __launch_bounds__(256) void k_gemm1(const float* __restrict__ x,
                                               const float* __restrict__ W1,
                                               const float* __restrict__ dinv,
                                               __half* __restrict__ hout) {
    __shared__ _Float16 Wl[8192];      // 16 KB, frag-ordered: [(nt*4+kc)*64+lane][8]
    const int tid = threadIdx.x, wave = tid >> 6, lane = tid & 63;
    const int quad = lane >> 4, m = lane & 15;
    // zero row at index N_NODES (padding target for k_gather1)
    if (blockIdx.x == 0 && tid < 32) ((int*)hout)[(size_t)N_NODES * 32 + tid] = 0;
    // repack W1 into B-fragment order (one-time)
    for (int it = 0; it < 16; ++it) {
        int p = it * 256 + tid;                 // 0..4095 half2-pairs
        int j2 = p & 3, ln = (p >> 2) & 63, kc = (p >> 8) & 3, nt = p >> 10;
        int k = kc * 32 + ((ln >> 4) << 3) + j2 * 2;
        int n = nt * 16 + (ln & 15);
        Wl[p * 2]     = (_Float16)W1[k * HID + n];
        Wl[p * 2 + 1] = (_Float16)W1[(k + 1) * HID + n];
    }
    __syncthreads();
    half8 bf[16];                               // B frags in VGPRs for whole kernel
    #pragma unroll
    for (int i = 0; i < 16; ++i) bf[i] = ((const half8*)Wl)[i * 64 + lane];

    const int ngroups = NBUCK;                  // 1563 groups of 64 nodes
    for (int g = blockIdx.x; g < ngroups; g += gridDim.x) {
        const int n0 = g * 64 + wave * 16;      // this wave's 16-node tile
        if (n0 >= N_NODES) continue;            // only last group's waves 2,3
        const float4* xrow = (const float4*)(x + (size_t)(n0 + m) * IN_F);
        f32x4 acc[4] = {{0.f,0.f,0.f,0.f},{0.f,0.f,0.f,0.f},
                        {0.f,0.f,0.f,0.f},{0.f,0.f,0.f,0.f}};
        #pragma unroll
        for (int kc = 0; kc < 4; ++kc) {
            float4 p0 = xrow[kc * 8 + quad * 2 + 0];   // A[m][kc*32+quad*8 .. +3]
            float4 p1 = xrow[kc * 8 + quad * 2 + 1];   // .. +4..+7
            half8 a;
            a[0] = (_Float16)p0.x; a[1] = (_Float16)p0.y;
            a[2] = (_Float16)p0.z; a[3] = (_Float16)p0.w;
            a[4] = (_Float16)p1.x; a[5] = (_Float16)p1.y;
            a[6] = (_Float16)p1.z; a[7] = (_Float16)p1.w;
            #pragma unroll
            for (int nt = 0; nt < 4; ++nt)
                acc[nt] = __builtin_amdgcn_mfma_f32_16x16x32_f16(a, bf[nt * 4 + kc], acc[nt], 0, 0, 0);
        }
        // epilogue: D[row=quad*4+r][col=lane&15] -> h[(n0+row)*64 + nt*16 + col]
        float di[4];
        #pragma unroll
        for (int r = 0; r < 4; ++r) di[r] = dinv[n0 + quad * 4 + r];
        _Float16* hp = (_Float16*)hout;
        #pragma unroll
        for (int nt = 0; nt < 4; ++nt)
            #pragma unroll
            for (int r = 0; r < 4; ++r)
                hp[(size_t)(n0 + quad * 4 + r) * HID + nt * 16 + m] =
                    (_Float16)(acc[nt][r] * di[r]);
    }
}

// ---------------- layer 1 gather + ReLU + GEMM2; TWO nodes per wave ----------------
// lanes 0-31 = node A, 32-63 = node B; within a half: grp2 = edge parity, fl = feature quad.
__global__ __launch_bounds__(256) void k_gather1(const __half* __restrict__ h1,
                                                 const int* __restrict__ off,
                                                 const int* __restrict__ csr,
                                                 const float* __restrict__ dinv,
                                                 const float* __restrict__ b1,
                                                 const float* __restrict__ W2,
                                                 float2* __restrict__ h2p) {
    const int wave = threadIdx.x >> 6, lane = threadIdx.x & 63;
    const int half = lane >> 5, l32 = lane & 31;
    const int grp2 = (lane >> 4) & 1, fl = lane & 15;
    const int d = blockIdx.x * 8 + wave * 2 + half;   // grid = 12501 blocks
    const bool valid = (d < N_NODES);
    if (d == N_NODES && l32 == 0) h2p[d] = make_float2(0.f, 0.f);   // zero row for gather2
    const int beg = valid ? off[d] : 0;
    const int end = valid ? off[d + 1] : 0;
    const int len = end - beg;
    int maxlen = max(len, __shfl_xor(len, 32, 64));   // max(lenA, lenB), wave-uniform
    const half4v* hrows = (const half4v*)h1;          // row r @ hrows[r*16 + fl]
    float a0 = 0.f, a1 = 0.f, a2 = 0.f, a3 = 0.f;
    for (int base = 0; base < maxlen; base += 32) {
        int idx = base + l32;
        int sidx = (idx < len) ? csr[beg + idx] : N_NODES;   // finished/OOB -> zero row
        const int cnt = min(32, maxlen - base);
        for (int j = 0; j < cnt; j += 8) {
            int ss[4];
            #pragma unroll
            for (int u = 0; u < 4; ++u)
                ss[u] = __shfl(sidx, (half << 5) | ((j + 2 * u + grp2) & 31), 64);
            half4v v[4];
            #pragma unroll
            for (int u = 0; u < 4; ++u)                 // 4 x 128B-row loads in flight
                v[u] = hrows[(size_t)ss[u] * 16 + fl];
            half2v p0 = {(_Float16)0.f, (_Float16)0.f};
            half2v p1 = {(_Float16)0.f, (_Float16)0.f};
            #pragma unroll
            for (int u = 0; u < 4; ++u) {               // v_pk_add_f16
                p0 += __builtin_shufflevector(v[u], v[u], 0, 1);
                p1 += __builtin_shufflevector(v[u], v[u], 2, 3);
            }
            a0 += (float)p0[0]; a1 += (float)p0[1];     // fp32 flush every 4 edges/lane
            a2 += (float)p1[0]; a3 += (float)p1[1];
        }
    }
    // merge the 2 parity groups (within each 32-lane half)
    a0 += __shfl_xor(a0, 16, 64);
    a1 += __shfl_xor(a1, 16, 64);
    a2 += __shfl_xor(a2, 16, 64);
    a3 += __shfl_xor(a3, 16, 64);
    if (!valid) return;
    // self-loop term
    half4v sv = hrows[(size_t)d * 16 + fl];
    a0 += (float)sv[0]; a1 += (float)sv[1]; a2 += (float)sv[2]; a3 += (float)sv[3];
    const float di = dinv[d];
    float4 bb = ((const float4*)b1)[fl];
    float y0 = fmaxf(di * a0 + bb.x, 0.f);
    float y1 = fmaxf(di * a1 + bb.y, 0.f);
    float y2 = fmaxf(di * a2 + bb.z, 0.f);
    float y3 = fmaxf(di * a3 + bb.w, 0.f);
    float4 w01 = ((const float4*)W2)[2 * fl];       // rows 4fl,4fl+1 (c0,c1 pairs)
    float4 w23 = ((const float4*)W2)[2 * fl + 1];   // rows 4fl+2,4fl+3
    float c0 = y0 * w01.x + y1 * w01.z + y2 * w23.x + y3 * w23.z;
    float c1 = y0 * w01.y + y1 * w01.w + y2 * w23.y + y3 * w23.w;
    #pragma unroll
    for (int o = 8; o > 0; o >>= 1) {               // reduce over fl bits only
        c0 += __shfl_xor(c0, o, 64);
        c1 += __shfl_xor(c1, o, 64);
    }
    if (l32 == 0) h2p[d] = make_float2(c0 * di, c1 * di);
}

// ---------------- layer 2 gather + finalize; 4 loads in flight (R13-proven) ----------
__global__ __launch_bounds__(256) void k_gather2(const float2* __restrict__ h2p,
                                                 const int* __restrict__ off,
                                                 const int* __restrict__ csr,
                                                 const float* __restrict__ dinv,
                                                 const float* __restrict__ b2,
                                                 float* __restrict__ out) {
    int i = blockIdx.x * 256 + threadIdx.x;
    if (i >= N_NODES) return;
    int beg = off[i], end = off[i + 1];
    float2 a = h2p[i];                                // self-loop term
    for (int s = beg; s < end; s += 4) {
        int node[4];
        #pragma unroll
        for (int u = 0; u < 4; ++u) {
            int idx = s + u;
            int n = csr[min(idx, end - 1)];           // always in-bounds load
            node[u] = (idx < end) ? n : N_NODES;      // padded -> zero row
        }
        float2 v[4];
        #pragma unroll
        for (int u = 0; u < 4; ++u) v[u] = h2p[node[u]];   // 4 loads in flight
        #pragma unroll
        for (int u = 0; u < 4; ++u) { a.x += v[u].x; a.y += v[u].y; }
    }
    float di = dinv[i];
    float2 o2 = make_float2(di * a.x + b2[0], di * a.y + b2[1]);
    ((float2*)out)[i] = o2;
}

extern "C" void kernel_launch(void* const* d_in, const int* in_sizes, int n_in,
                              void* d_out, int out_size, void* d_ws, size_t ws_size,
                              hipStream_t stream) {
    const float* x  = (const float*)d_in[0];
    const int*   ei = (const int*)d_in[1];
    const float* W1 = (const float*)d_in[2];
    const float* b1 = (const float*)d_in[3];
    const float* W2 = (const float*)d_in[4];
    const float* b2 = (const float*)d_in[5];
    float* out = (float*)d_out;

    const int* src = ei;
    const int* dst = ei + N_EDGES;

    // workspace layout (int units; no aliasing; ~30.5 MB)
    int*            wsi   = (int*)d_ws;
    unsigned short* gcnt  = (unsigned short*)wsi;            // 512x1600 u16
    unsigned short* pre   = (unsigned short*)(wsi + 409600);
    int*            bt    = wsi + 819200;                    // 2048
    int*            bbase = wsi + 821248;                    // 2048
    int*            off   = wsi + 823296;                    // 100352 (N+1 used)
    float*          dinv  = (float*)(wsi + 923648);          // 100352
    int*            bin   = wsi + 1024000;                   // 1600000
    int*            csr   = wsi + 2624000;                   // 1600000
    __half*         h1p   = (__half*)(wsi + 4224000);        // 100001 rows x 128 B
    float2*         h2p   = (float2*)(wsi + 7424064);        // 100001 float2

    dim3 B(256);
    k_hist_g <<<GS, B, 0, stream>>>(dst, gcnt);
    k_gbase  <<<196, 512, 0, stream>>>(gcnt, pre, bt);       // 196*8 = 1568 buckets
    k_bscan  <<<1, 1024, 0, stream>>>(bt, bbase, off);
    k_bin    <<<GS, B, 0, stream>>>(src, dst, bbase, pre, bin);
    k_csr    <<<NBUCK, B, 0, stream>>>(bin, bbase, off, dinv, csr);

    k_gemm1  <<<512, B, 0, stream>>>(x, W1, dinv, h1p);
    k_gather1<<<12501, B, 0, stream>>>(h1p, off, csr, dinv, b1, W2, h2p);
    k_gather2<<<(N_NODES + 255) / 256, B, 0, stream>>>(h2p, off, csr, dinv, b2, out);
}